// Round 3
// baseline (259.753 us; speedup 1.0000x reference)
//
#include <hip/hip_runtime.h>
#include <stdint.h>

typedef short short8 __attribute__((ext_vector_type(8)));
typedef float f32x4 __attribute__((ext_vector_type(4)));

__device__ inline float b2f(unsigned short u) {
    union { float f; uint32_t i; } v; v.i = ((uint32_t)u) << 16; return v.f;
}
__device__ inline unsigned short f2b(float f) {
    union { float f; uint32_t i; } v; v.f = f;
    uint32_t r = v.i + 0x7FFFu + ((v.i >> 16) & 1u);
    return (unsigned short)(r >> 16);
}

#define BB 8
#define NN 1024
#define HH 128
#define EE 4
#define MROWS (BB * NN)      // 8192
#define NBR_CAP 96
#define RPB 32               // rows per block in step/mlp kernels

// ============ setup: init h/hb/nfb + all weights -> bf16 fragment-major ============
// B-fragment layout for mfma_f32_16x16x32_bf16:
//   wf[(((s*NF + f)*64 + l)*8 + j)] = W[col = f*16 + (l&15)][k = s*32 + (l>>4)*8 + j]
__global__ __launch_bounds__(256) void setup(
    const float* __restrict__ nf, const float* __restrict__ We,
    const float* __restrict__ Wih, const float* __restrict__ Whh,
    const float* __restrict__ W1, const float* __restrict__ W2,
    float* __restrict__ h, unsigned short* __restrict__ hb,
    unsigned short* __restrict__ nfb,
    unsigned short* __restrict__ wcf, unsigned short* __restrict__ wgf,
    unsigned short* __restrict__ w1f, unsigned short* __restrict__ w2f)
{
    int tid = blockIdx.x * 256 + threadIdx.x;   // 1,048,576 threads
    {   // state init (all threads cover MROWS*128)
        float v = nf[tid];
        h[tid] = v;
        unsigned short b = f2b(v);
        hb[tid] = b;
        nfb[tid] = b;
    }
    // wgf: Wg(512 x 256) fragment-major (NF=32, s=0..7)
    if (tid < 131072) {
        int j = tid & 7, l = (tid >> 3) & 63, f = (tid >> 9) & 31, s = tid >> 14;
        int col = f * 16 + (l & 15);            // 0..511 (gate col: r|z|i_n|h_n)
        int k   = s * 32 + ((l >> 4) << 3) + j; // 0..255
        int kr = k & 127;
        float v;
        if (col < 256)      v = (k < 128) ? Wih[col * 128 + kr] : Whh[col * 128 + kr];
        else if (col < 384) v = (k < 128) ? Wih[col * 128 + kr] : 0.f;
        else                v = (k < 128) ? 0.f : Whh[(col - 128) * 128 + kr];
        wgf[tid] = f2b(v);
    }
    // wcf: Wc(128 x 512) fragment-major (NF=8, s=0..15); Wc[c][(e,hh)] = We[e][c][hh]
    if (tid < 65536) {
        int j = tid & 7, l = (tid >> 3) & 63, f = (tid >> 9) & 7, s = tid >> 12;
        int col = f * 16 + (l & 15);
        int k   = s * 32 + ((l >> 4) << 3) + j; // 0..511
        int e = k >> 7, hh2 = k & 127;
        wcf[tid] = f2b(We[(e << 14) + (col << 7) + hh2]);
    }
    // w1f: W1(128 x 256) (NF=8, s=0..7)
    if (tid < 32768) {
        int j = tid & 7, l = (tid >> 3) & 63, f = (tid >> 9) & 7, s = tid >> 12;
        int col = f * 16 + (l & 15);
        int k   = s * 32 + ((l >> 4) << 3) + j;
        w1f[tid] = f2b(W1[col * 256 + k]);
    }
    // w2f: W2(128 x 128) (NF=8, s=0..3)
    if (tid < 16384) {
        int j = tid & 7, l = (tid >> 3) & 63, f = (tid >> 9) & 7, s = tid >> 12;
        int col = f * 16 + (l & 15);
        int k   = s * 32 + ((l >> 4) << 3) + j;
        w2f[tid] = f2b(W2[col * 128 + k]);
    }
}

// ============ sparsify: one wave per (b,e,i) row ============
__global__ __launch_bounds__(256) void sparsify(
    const float* __restrict__ adj, unsigned short* __restrict__ cols,
    int* __restrict__ cnt)
{
    int row = blockIdx.x * 4 + (threadIdx.x >> 6);  // 32768 rows
    int l = threadIdx.x & 63;
    const float* ar = adj + (size_t)row * NN;
    unsigned short* cr = cols + (size_t)row * NBR_CAP;
    int c = 0;
    for (int it = 0; it < 4; ++it) {
        float4 v = *(const float4*)(ar + it * 256 + l * 4);
        const float* vp = &v.x;
        #pragma unroll
        for (int p = 0; p < 4; ++p) {
            float x = vp[p];
            unsigned long long m = __ballot(x != 0.f);
            if (x != 0.f) {
                int idx = c + __popcll(m & ((1ull << l) - 1ull));
                if (idx < NBR_CAP) cr[idx] = (unsigned short)(it * 256 + l * 4 + p);
            }
            c += __popcll(m);
        }
    }
    if (l == 0) cnt[row] = c < NBR_CAP ? c : NBR_CAP;
}

// ============ fused step: aggregate -> combine -> gates -> GRU ============
// 256 blocks x 512 threads (8 waves); each block owns 32 rows.
// hb ping-pong: reads hb_in (ALL rows, prev step), writes hb_out (own rows).
__global__ __launch_bounds__(512) void step_k(
    const unsigned short* __restrict__ cols, const int* __restrict__ cnt,
    const unsigned short* __restrict__ hb_in, unsigned short* __restrict__ hb_out,
    float* __restrict__ h_g,
    const unsigned short* __restrict__ wcf, const unsigned short* __restrict__ wgf,
    const float* __restrict__ bih, const float* __restrict__ bhh)
{
    __shared__ unsigned short s_ab[32 * 520];  // 33,280 B  (stride 520: 2-way banks)
    __shared__ unsigned short s_m[32 * 136];   //  8,704 B
    __shared__ unsigned short s_hb[32 * 136];  //  8,704 B
    __shared__ float s_g[32 * 520];            // 66,560 B  (stride%32==8: 2-way)
    __shared__ float s_bg[512];                //  2,048 B   => total 119,296 B
    const int t = threadIdx.x, l = t & 63, wv = t >> 6;
    const int lr = l & 15;
    const int ak = (l >> 4) * 8;
    const int bm = blockIdx.x * RPB;
    const int b = bm >> 10, i0 = bm & 1023;

    // ---- phase 0: own h rows -> regs; s_hb = bf16(h); combined bias -> s_bg ----
    float hreg[8];
    #pragma unroll
    for (int it = 0; it < 8; ++it) {
        int idx = it * 512 + t, row = idx >> 7, k = idx & 127;
        float v = h_g[(size_t)(bm + row) * 128 + k];
        hreg[it] = v;
        s_hb[row * 136 + k] = f2b(v);
    }
    {
        int k = t & 127, sec = t >> 7;
        float v;
        if (sec == 0)      v = bih[k] + bhh[k];
        else if (sec == 1) v = bih[128 + k] + bhh[128 + k];
        else if (sec == 2) v = bih[256 + k];
        else               v = bhh[256 + k];
        s_bg[t] = v;
    }

    // ---- phase A: aggregate own 32 rows x 4 edge types into s_ab ----
    // wave wv handles pairs p = wv*16 .. wv*16+15 (p = rl*4 + e), 2 at a time for ILP
    const int l2 = l * 2;
    const unsigned short* hbase = hb_in + ((size_t)(b << 10)) * 128 + l2;
    for (int pi = 0; pi < 16; pi += 2) {
        int p0 = wv * 16 + pi, p1 = p0 + 1;
        int rl0 = p0 >> 2, e0 = p0 & 3;
        int rl1 = p1 >> 2, e1 = p1 & 3;
        int ar0 = ((b * 4 + e0) << 10) + i0 + rl0;
        int ar1 = ((b * 4 + e1) << 10) + i0 + rl1;
        int c0 = cnt[ar0], c1 = cnt[ar1];
        const unsigned short* q0 = cols + (size_t)ar0 * NBR_CAP;
        const unsigned short* q1 = cols + (size_t)ar1 * NBR_CAP;
        float a00 = 0.f, a01 = 0.f, a10 = 0.f, a11 = 0.f;
        int cm = c0 > c1 ? c0 : c1;
        for (int q = 0; q < cm; ++q) {
            if (q < c0) {
                uint32_t v = *(const uint32_t*)(hbase + (size_t)q0[q] * 128);
                a00 += b2f((unsigned short)(v & 0xffffu)); a01 += b2f((unsigned short)(v >> 16));
            }
            if (q < c1) {
                uint32_t v = *(const uint32_t*)(hbase + (size_t)q1[q] * 128);
                a10 += b2f((unsigned short)(v & 0xffffu)); a11 += b2f((unsigned short)(v >> 16));
            }
        }
        *(uint32_t*)&s_ab[rl0 * 520 + e0 * 128 + l2] = (uint32_t)f2b(a00) | ((uint32_t)f2b(a01) << 16);
        *(uint32_t*)&s_ab[rl1 * 520 + e1 * 128 + l2] = (uint32_t)f2b(a10) | ((uint32_t)f2b(a11) << 16);
    }
    __syncthreads();

    // ---- phase B: m(32x128) = s_ab(32x512) @ Wc^T ; wave wv -> cols 16*wv.. ----
    f32x4 accB[2] = {};
    #pragma unroll
    for (int s = 0; s < 16; ++s) {
        short8 af0 = *(const short8*)&s_ab[lr * 520 + s * 32 + ak];
        short8 af1 = *(const short8*)&s_ab[(16 + lr) * 520 + s * 32 + ak];
        short8 bf = *(const short8*)(wcf + (((size_t)s * 8 + wv) * 64 + l) * 8);
        accB[0] = __builtin_amdgcn_mfma_f32_16x16x32_bf16(af0, bf, accB[0], 0, 0, 0);
        accB[1] = __builtin_amdgcn_mfma_f32_16x16x32_bf16(af1, bf, accB[1], 0, 0, 0);
    }
    {
        int col = wv * 16 + lr;
        #pragma unroll
        for (int mi = 0; mi < 2; ++mi)
            #pragma unroll
            for (int r = 0; r < 4; ++r)
                s_m[(mi * 16 + (l >> 4) * 4 + r) * 136 + col] = f2b(accB[mi][r]);
    }
    __syncthreads();

    // ---- phase C: gates(32x512) = [m|h](32x256) @ Wg^T ; wave wv -> 4 col-frags ----
    f32x4 accC[2][4] = {};
    #pragma unroll
    for (int s = 0; s < 8; ++s) {
        short8 af0, af1;
        if (s < 4) {
            af0 = *(const short8*)&s_m[lr * 136 + s * 32 + ak];
            af1 = *(const short8*)&s_m[(16 + lr) * 136 + s * 32 + ak];
        } else {
            af0 = *(const short8*)&s_hb[lr * 136 + (s - 4) * 32 + ak];
            af1 = *(const short8*)&s_hb[(16 + lr) * 136 + (s - 4) * 32 + ak];
        }
        #pragma unroll
        for (int ni = 0; ni < 4; ++ni) {
            int f = wv * 4 + ni;
            short8 bf = *(const short8*)(wgf + (((size_t)s * 32 + f) * 64 + l) * 8);
            accC[0][ni] = __builtin_amdgcn_mfma_f32_16x16x32_bf16(af0, bf, accC[0][ni], 0, 0, 0);
            accC[1][ni] = __builtin_amdgcn_mfma_f32_16x16x32_bf16(af1, bf, accC[1][ni], 0, 0, 0);
        }
    }
    #pragma unroll
    for (int ni = 0; ni < 4; ++ni) {
        int col = (wv * 4 + ni) * 16 + lr;
        #pragma unroll
        for (int mi = 0; mi < 2; ++mi)
            #pragma unroll
            for (int r = 0; r < 4; ++r)
                s_g[(mi * 16 + (l >> 4) * 4 + r) * 520 + col] = accC[mi][ni][r];
    }
    __syncthreads();

    // ---- phase D: GRU elementwise; write h_g (own) + hb_out (own) ----
    #pragma unroll
    for (int it = 0; it < 8; ++it) {
        int idx = it * 512 + t, row = idx >> 7, k = idx & 127;
        float rt = s_g[row * 520 + k]       + s_bg[k];
        float zt = s_g[row * 520 + 128 + k] + s_bg[128 + k];
        float nn = s_g[row * 520 + 256 + k] + s_bg[256 + k];
        float hn = s_g[row * 520 + 384 + k] + s_bg[384 + k];
        float rr = 1.f / (1.f + __expf(-rt));
        float zz = 1.f / (1.f + __expf(-zt));
        float n = tanhf(nn + rr * hn);
        float hv = (1.f - zz) * n + zz * hreg[it];
        size_t gidx = (size_t)(bm + row) * 128 + k;
        h_g[gidx] = hv;
        hb_out[gidx] = f2b(hv);
    }
}

// ============ MLP: y = relu([nf|h] @ W1^T + b1); out = y @ W2^T + b2 ============
__global__ __launch_bounds__(512) void mlp_k(
    const unsigned short* __restrict__ nfb, const unsigned short* __restrict__ hbg,
    const unsigned short* __restrict__ w1f, const float* __restrict__ b1,
    const unsigned short* __restrict__ w2f, const float* __restrict__ b2,
    float* __restrict__ out)
{
    __shared__ unsigned short s_x[32 * 264];
    __shared__ unsigned short s_y[32 * 136];
    const int t = threadIdx.x, l = t & 63, wv = t >> 6;
    const int lr = l & 15;
    const int ak = (l >> 4) * 8;
    const int bm = blockIdx.x * RPB;
    for (int ci = t; ci < 1024; ci += 512) {
        int row = ci >> 5, col = (ci & 31) * 8;
        const unsigned short* src = (col < 128)
            ? nfb + (size_t)(bm + row) * 128 + col
            : hbg + (size_t)(bm + row) * 128 + (col - 128);
        *(short8*)&s_x[row * 264 + col] = *(const short8*)src;
    }
    __syncthreads();
    f32x4 acc[2] = {};
    #pragma unroll
    for (int s = 0; s < 8; ++s) {
        short8 af0 = *(const short8*)&s_x[lr * 264 + s * 32 + ak];
        short8 af1 = *(const short8*)&s_x[(16 + lr) * 264 + s * 32 + ak];
        short8 bf = *(const short8*)(w1f + (((size_t)s * 8 + wv) * 64 + l) * 8);
        acc[0] = __builtin_amdgcn_mfma_f32_16x16x32_bf16(af0, bf, acc[0], 0, 0, 0);
        acc[1] = __builtin_amdgcn_mfma_f32_16x16x32_bf16(af1, bf, acc[1], 0, 0, 0);
    }
    const int col = wv * 16 + lr;
    {
        float b1v = b1[col];
        #pragma unroll
        for (int mi = 0; mi < 2; ++mi)
            #pragma unroll
            for (int r = 0; r < 4; ++r) {
                float v = acc[mi][r] + b1v;
                s_y[(mi * 16 + (l >> 4) * 4 + r) * 136 + col] = f2b(v > 0.f ? v : 0.f);
            }
    }
    __syncthreads();
    f32x4 acc2[2] = {};
    #pragma unroll
    for (int s = 0; s < 4; ++s) {
        short8 af0 = *(const short8*)&s_y[lr * 136 + s * 32 + ak];
        short8 af1 = *(const short8*)&s_y[(16 + lr) * 136 + s * 32 + ak];
        short8 bf = *(const short8*)(w2f + (((size_t)s * 8 + wv) * 64 + l) * 8);
        acc2[0] = __builtin_amdgcn_mfma_f32_16x16x32_bf16(af0, bf, acc2[0], 0, 0, 0);
        acc2[1] = __builtin_amdgcn_mfma_f32_16x16x32_bf16(af1, bf, acc2[1], 0, 0, 0);
    }
    float b2v = b2[col];
    #pragma unroll
    for (int mi = 0; mi < 2; ++mi)
        #pragma unroll
        for (int r = 0; r < 4; ++r)
            out[(size_t)(bm + mi * 16 + (l >> 4) * 4 + r) * 128 + col] = acc2[mi][r] + b2v;
}

// ============ host launcher ============
extern "C" void kernel_launch(void* const* d_in, const int* in_sizes, int n_in,
                              void* d_out, int out_size, void* d_ws, size_t ws_size,
                              hipStream_t stream) {
    const float* nf  = (const float*)d_in[0];
    const float* adj = (const float*)d_in[1];
    const float* We  = (const float*)d_in[2];
    const float* Wih = (const float*)d_in[3];
    const float* Whh = (const float*)d_in[4];
    const float* bih = (const float*)d_in[5];
    const float* bhh = (const float*)d_in[6];
    const float* W1  = (const float*)d_in[7];
    const float* b1  = (const float*)d_in[8];
    const float* W2  = (const float*)d_in[9];
    const float* b2  = (const float*)d_in[10];
    float* out = (float*)d_out;

    char* p = (char*)d_ws;
    auto take = [&](size_t n) { char* r = p; p += (n + 255) & ~(size_t)255; return r; };
    int* cnt             = (int*)take(32768 * 4);
    unsigned short* cols = (unsigned short*)take((size_t)32768 * NBR_CAP * 2);
    float* h_g           = (float*)take((size_t)MROWS * 128 * 4);
    unsigned short* hbA  = (unsigned short*)take((size_t)MROWS * 128 * 2);
    unsigned short* hbB  = (unsigned short*)take((size_t)MROWS * 128 * 2);
    unsigned short* nfb  = (unsigned short*)take((size_t)MROWS * 128 * 2);
    unsigned short* wcf  = (unsigned short*)take(65536 * 2);
    unsigned short* wgf  = (unsigned short*)take(131072 * 2);
    unsigned short* w1f  = (unsigned short*)take(32768 * 2);
    unsigned short* w2f  = (unsigned short*)take(16384 * 2);

    setup<<<4096, 256, 0, stream>>>(nf, We, Wih, Whh, W1, W2,
                                    h_g, hbA, nfb, wcf, wgf, w1f, w2f);
    sparsify<<<8192, 256, 0, stream>>>(adj, cols, cnt);

    // hb ping-pong: step s reads hb[s%2], writes hb[(s+1)%2]
    step_k<<<256, 512, 0, stream>>>(cols, cnt, hbA, hbB, h_g, wcf, wgf, bih, bhh);
    step_k<<<256, 512, 0, stream>>>(cols, cnt, hbB, hbA, h_g, wcf, wgf, bih, bhh);
    step_k<<<256, 512, 0, stream>>>(cols, cnt, hbA, hbB, h_g, wcf, wgf, bih, bhh);

    mlp_k<<<256, 512, 0, stream>>>(nfb, hbB, w1f, b1, w2f, b2, out);
}

// Round 4
// 123.134 us; speedup vs baseline: 2.1095x; 2.1095x over previous
//
#include <hip/hip_runtime.h>
#include <stdint.h>

typedef short short8 __attribute__((ext_vector_type(8)));
typedef float f32x4 __attribute__((ext_vector_type(4)));

__device__ inline float b2f(unsigned short u) {
    union { float f; uint32_t i; } v; v.i = ((uint32_t)u) << 16; return v.f;
}
__device__ inline unsigned short f2b(float f) {
    union { float f; uint32_t i; } v; v.f = f;
    uint32_t r = v.i + 0x7FFFu + ((v.i >> 16) & 1u);
    return (unsigned short)(r >> 16);
}

#define BB 8
#define NN 1024
#define HH 128
#define EE 4
#define MROWS (BB * NN)      // 8192
#define NBR_CAP 96
#define RPB 32

// ============ combo: sparsify (blocks 0..8191) + setup (blocks 8192..12287) ============
__global__ __launch_bounds__(256) void combo(
    const float* __restrict__ adj, unsigned short* __restrict__ cols,
    int* __restrict__ cnt,
    const float* __restrict__ nf, const float* __restrict__ We,
    const float* __restrict__ Wih, const float* __restrict__ Whh,
    const float* __restrict__ bih, const float* __restrict__ bhh,
    const float* __restrict__ W1, const float* __restrict__ W2,
    float* __restrict__ h, unsigned short* __restrict__ hb,
    unsigned short* __restrict__ nfb,
    unsigned short* __restrict__ wcf, unsigned short* __restrict__ wgf,
    unsigned short* __restrict__ w1f, unsigned short* __restrict__ w2f,
    float* __restrict__ bg)
{
    if (blockIdx.x < 8192) {
        // ---- sparsify: one wave per (b,e,i) row ----
        int row = blockIdx.x * 4 + (threadIdx.x >> 6);
        int l = threadIdx.x & 63;
        const float* ar = adj + (size_t)row * NN;
        unsigned short* cr = cols + (size_t)row * NBR_CAP;
        int c = 0;
        for (int it = 0; it < 4; ++it) {
            float4 v = *(const float4*)(ar + it * 256 + l * 4);
            const float* vp = &v.x;
            #pragma unroll
            for (int p = 0; p < 4; ++p) {
                float x = vp[p];
                unsigned long long m = __ballot(x != 0.f);
                if (x != 0.f) {
                    int idx = c + __popcll(m & ((1ull << l) - 1ull));
                    if (idx < NBR_CAP) cr[idx] = (unsigned short)(it * 256 + l * 4 + p);
                }
                c += __popcll(m);
            }
        }
        if (l == 0) cnt[row] = c < NBR_CAP ? c : NBR_CAP;
        return;
    }
    // ---- setup ----
    int tid = (blockIdx.x - 8192) * 256 + threadIdx.x;   // 0..1,048,575
    {
        float v = nf[tid];
        h[tid] = v;
        unsigned short b = f2b(v);
        hb[tid] = b;
        nfb[tid] = b;
    }
    // wgf: Wg(512 x 256) fragment-major (NF=32, s=0..7)
    if (tid < 131072) {
        int j = tid & 7, l = (tid >> 3) & 63, f = (tid >> 9) & 31, s = tid >> 14;
        int col = f * 16 + (l & 15);            // gate col: r|z|i_n|h_n
        int k   = s * 32 + ((l >> 4) << 3) + j; // 0..255
        int kr = k & 127;
        float v;
        if (col < 256)      v = (k < 128) ? Wih[col * 128 + kr] : Whh[col * 128 + kr];
        else if (col < 384) v = (k < 128) ? Wih[col * 128 + kr] : 0.f;
        else                v = (k < 128) ? 0.f : Whh[(col - 128) * 128 + kr];
        wgf[tid] = f2b(v);
    }
    // wcf: Wc(128 x 512) fragment-major (NF=8, s=0..15); Wc[c][(e,hh)] = We[e][c][hh]
    if (tid < 65536) {
        int j = tid & 7, l = (tid >> 3) & 63, f = (tid >> 9) & 7, s = tid >> 12;
        int col = f * 16 + (l & 15);
        int k   = s * 32 + ((l >> 4) << 3) + j; // 0..511
        int e = k >> 7, hh2 = k & 127;
        wcf[tid] = f2b(We[(e << 14) + (col << 7) + hh2]);
    }
    // w1f: W1(128 x 256) (NF=8, s=0..7)
    if (tid < 32768) {
        int j = tid & 7, l = (tid >> 3) & 63, f = (tid >> 9) & 7, s = tid >> 12;
        int col = f * 16 + (l & 15);
        int k   = s * 32 + ((l >> 4) << 3) + j;
        w1f[tid] = f2b(W1[col * 256 + k]);
    }
    // w2f: W2(128 x 128) (NF=8, s=0..3)
    if (tid < 16384) {
        int j = tid & 7, l = (tid >> 3) & 63, f = (tid >> 9) & 7, s = tid >> 12;
        int col = f * 16 + (l & 15);
        int k   = s * 32 + ((l >> 4) << 3) + j;
        w2f[tid] = f2b(W2[col * 128 + k]);
    }
    // bg[512]: combined bias (r,z use bih+bhh; i_n uses bih; h_n uses bhh)
    if (tid < 512) {
        int sec = tid >> 7, k = tid & 127;
        float v;
        if (sec == 0)      v = bih[k] + bhh[k];
        else if (sec == 1) v = bih[128 + k] + bhh[128 + k];
        else if (sec == 2) v = bih[256 + k];
        else               v = bhh[256 + k];
        bg[tid] = v;
    }
}

// ============ aggregate: ab[(b,i),(e,h)] = sum_j hb[b,j,h]; 8-deep MLP ============
__global__ __launch_bounds__(256) void aggregate(
    const unsigned short* __restrict__ hb, const unsigned short* __restrict__ cols,
    const int* __restrict__ cnt, unsigned short* __restrict__ ab)
{
    int bi = blockIdx.x;                 // b*N + i
    int b = bi >> 10;
    int e = threadIdx.x >> 6;
    int l2 = (threadIdx.x & 63) * 2;
    int row = ((b << 2) + e) * NN + (bi & 1023);
    int c = cnt[row];
    const unsigned short* cl = cols + (size_t)row * NBR_CAP;
    const unsigned short* hbase = hb + ((size_t)(b << 10)) * HH + l2;
    float a0 = 0.f, a1 = 0.f;
    int q = 0;
    for (; q + 8 <= c; q += 8) {
        uint4 iv = *(const uint4*)(cl + q);   // 8 indices, 16B-aligned
        uint32_t j0 = iv.x & 0xffffu, j1 = iv.x >> 16;
        uint32_t j2 = iv.y & 0xffffu, j3 = iv.y >> 16;
        uint32_t j4 = iv.z & 0xffffu, j5 = iv.z >> 16;
        uint32_t j6 = iv.w & 0xffffu, j7 = iv.w >> 16;
        uint32_t v0 = *(const uint32_t*)(hbase + (size_t)j0 * HH);
        uint32_t v1 = *(const uint32_t*)(hbase + (size_t)j1 * HH);
        uint32_t v2 = *(const uint32_t*)(hbase + (size_t)j2 * HH);
        uint32_t v3 = *(const uint32_t*)(hbase + (size_t)j3 * HH);
        uint32_t v4 = *(const uint32_t*)(hbase + (size_t)j4 * HH);
        uint32_t v5 = *(const uint32_t*)(hbase + (size_t)j5 * HH);
        uint32_t v6 = *(const uint32_t*)(hbase + (size_t)j6 * HH);
        uint32_t v7 = *(const uint32_t*)(hbase + (size_t)j7 * HH);
        a0 += b2f((unsigned short)(v0 & 0xffffu)); a1 += b2f((unsigned short)(v0 >> 16));
        a0 += b2f((unsigned short)(v1 & 0xffffu)); a1 += b2f((unsigned short)(v1 >> 16));
        a0 += b2f((unsigned short)(v2 & 0xffffu)); a1 += b2f((unsigned short)(v2 >> 16));
        a0 += b2f((unsigned short)(v3 & 0xffffu)); a1 += b2f((unsigned short)(v3 >> 16));
        a0 += b2f((unsigned short)(v4 & 0xffffu)); a1 += b2f((unsigned short)(v4 >> 16));
        a0 += b2f((unsigned short)(v5 & 0xffffu)); a1 += b2f((unsigned short)(v5 >> 16));
        a0 += b2f((unsigned short)(v6 & 0xffffu)); a1 += b2f((unsigned short)(v6 >> 16));
        a0 += b2f((unsigned short)(v7 & 0xffffu)); a1 += b2f((unsigned short)(v7 >> 16));
    }
    for (; q < c; ++q) {
        uint32_t v = *(const uint32_t*)(hbase + (size_t)cl[q] * HH);
        a0 += b2f((unsigned short)(v & 0xffffu)); a1 += b2f((unsigned short)(v >> 16));
    }
    *(uint32_t*)(ab + ((size_t)bi * EE + e) * HH + l2) =
        (uint32_t)f2b(a0) | ((uint32_t)f2b(a1) << 16);
}

// ============ step2: combine-GEMM + gates-GEMM + register GRU ============
// 256 blocks x 512 thr (8 waves), 32 rows/block, LDS ~51KB -> 3 blocks/CU capacity
__global__ __launch_bounds__(512) void step2(
    const unsigned short* __restrict__ ab_g, unsigned short* __restrict__ hb,
    float* __restrict__ h_g,
    const unsigned short* __restrict__ wcf, const unsigned short* __restrict__ wgf,
    const float* __restrict__ bg)
{
    __shared__ unsigned short s_ab[32 * 520];  // 33,280 B
    __shared__ unsigned short s_m[32 * 136];   //  8,704 B
    __shared__ unsigned short s_hb[32 * 136];  //  8,704 B
    const int t = threadIdx.x, l = t & 63, wv = t >> 6;
    const int lr = l & 15;
    const int ak = (l >> 4) * 8;
    const int bm = blockIdx.x * RPB;
    const int kk = wv * 16 + lr;               // this wave's k-column

    // bias regs (loaded early; used in phase D)
    float bgr = bg[kk], bgz = bg[128 + kk], bgn = bg[256 + kk], bgh = bg[384 + kk];

    // ---- stage s_ab (32x512) + s_hb (32x128) ----
    #pragma unroll
    for (int ci = 0; ci < 4; ++ci) {
        int idx = ci * 512 + t;
        int row = idx >> 6, ch = (idx & 63) * 8;
        *(short8*)&s_ab[row * 520 + ch] = *(const short8*)(ab_g + (size_t)(bm + row) * 512 + ch);
    }
    {
        int row = t >> 4, ch = (t & 15) * 8;
        *(short8*)&s_hb[row * 136 + ch] = *(const short8*)(hb + (size_t)(bm + row) * 128 + ch);
    }
    __syncthreads();

    // ---- phase B: m(32x128) = s_ab @ Wc^T ; wave wv -> cols wv*16.. ----
    f32x4 accB[2] = {};
    {
        short8 bf_cur = *(const short8*)(wcf + (((size_t)0 * 8 + wv) * 64 + l) * 8);
        #pragma unroll
        for (int s = 0; s < 16; ++s) {
            short8 bf_next;
            if (s < 15) bf_next = *(const short8*)(wcf + (((size_t)(s + 1) * 8 + wv) * 64 + l) * 8);
            short8 af0 = *(const short8*)&s_ab[lr * 520 + s * 32 + ak];
            short8 af1 = *(const short8*)&s_ab[(16 + lr) * 520 + s * 32 + ak];
            accB[0] = __builtin_amdgcn_mfma_f32_16x16x32_bf16(af0, bf_cur, accB[0], 0, 0, 0);
            accB[1] = __builtin_amdgcn_mfma_f32_16x16x32_bf16(af1, bf_cur, accB[1], 0, 0, 0);
            if (s < 15) bf_cur = bf_next;
        }
    }
    #pragma unroll
    for (int mi = 0; mi < 2; ++mi)
        #pragma unroll
        for (int r = 0; r < 4; ++r)
            s_m[(mi * 16 + (l >> 4) * 4 + r) * 136 + kk] = f2b(accB[mi][r]);
    __syncthreads();

    // ---- phase C: gates; wave wv takes B-frags f = g*8+wv (g = gate section) ----
    // acc[mi][g][r] = G[row][g*128 + kk] -> all 4 gates per (row,kk) live in-lane
    f32x4 accC[2][4] = {};
    {
        short8 cf[4], nf_[4];
        #pragma unroll
        for (int g = 0; g < 4; ++g)
            cf[g] = *(const short8*)(wgf + (((size_t)0 * 32 + g * 8 + wv) * 64 + l) * 8);
        #pragma unroll
        for (int s = 0; s < 8; ++s) {
            if (s < 7) {
                #pragma unroll
                for (int g = 0; g < 4; ++g)
                    nf_[g] = *(const short8*)(wgf + (((size_t)(s + 1) * 32 + g * 8 + wv) * 64 + l) * 8);
            }
            short8 af0, af1;
            if (s < 4) {
                af0 = *(const short8*)&s_m[lr * 136 + s * 32 + ak];
                af1 = *(const short8*)&s_m[(16 + lr) * 136 + s * 32 + ak];
            } else {
                af0 = *(const short8*)&s_hb[lr * 136 + (s - 4) * 32 + ak];
                af1 = *(const short8*)&s_hb[(16 + lr) * 136 + (s - 4) * 32 + ak];
            }
            #pragma unroll
            for (int g = 0; g < 4; ++g) {
                accC[0][g] = __builtin_amdgcn_mfma_f32_16x16x32_bf16(af0, cf[g], accC[0][g], 0, 0, 0);
                accC[1][g] = __builtin_amdgcn_mfma_f32_16x16x32_bf16(af1, cf[g], accC[1][g], 0, 0, 0);
            }
            if (s < 7) {
                #pragma unroll
                for (int g = 0; g < 4; ++g) cf[g] = nf_[g];
            }
        }
    }

    // ---- phase D: register GRU (no LDS, no barrier) ----
    float ho[2][4];
    #pragma unroll
    for (int mi = 0; mi < 2; ++mi)
        #pragma unroll
        for (int r = 0; r < 4; ++r)
            ho[mi][r] = h_g[(size_t)(bm + mi * 16 + (l >> 4) * 4 + r) * 128 + kk];
    #pragma unroll
    for (int mi = 0; mi < 2; ++mi)
        #pragma unroll
        for (int r = 0; r < 4; ++r) {
            float rr = 1.f / (1.f + __expf(-(accC[mi][0][r] + bgr)));
            float zz = 1.f / (1.f + __expf(-(accC[mi][1][r] + bgz)));
            float n  = tanhf(accC[mi][2][r] + bgn + rr * (accC[mi][3][r] + bgh));
            float hv = (1.f - zz) * n + zz * ho[mi][r];
            size_t gidx = (size_t)(bm + mi * 16 + (l >> 4) * 4 + r) * 128 + kk;
            h_g[gidx] = hv;
            hb[gidx]  = f2b(hv);
        }
}

// ============ MLP: y = relu([nf|h] @ W1^T + b1); out = y @ W2^T + b2 ============
__global__ __launch_bounds__(512) void mlp_k(
    const unsigned short* __restrict__ nfb, const unsigned short* __restrict__ hbg,
    const unsigned short* __restrict__ w1f, const float* __restrict__ b1,
    const unsigned short* __restrict__ w2f, const float* __restrict__ b2,
    float* __restrict__ out)
{
    __shared__ unsigned short s_x[32 * 264];
    __shared__ unsigned short s_y[32 * 136];
    const int t = threadIdx.x, l = t & 63, wv = t >> 6;
    const int lr = l & 15;
    const int ak = (l >> 4) * 8;
    const int bm = blockIdx.x * RPB;
    for (int ci = t; ci < 1024; ci += 512) {
        int row = ci >> 5, col = (ci & 31) * 8;
        const unsigned short* src = (col < 128)
            ? nfb + (size_t)(bm + row) * 128 + col
            : hbg + (size_t)(bm + row) * 128 + (col - 128);
        *(short8*)&s_x[row * 264 + col] = *(const short8*)src;
    }
    __syncthreads();
    f32x4 acc[2] = {};
    {
        short8 bf_cur = *(const short8*)(w1f + (((size_t)0 * 8 + wv) * 64 + l) * 8);
        #pragma unroll
        for (int s = 0; s < 8; ++s) {
            short8 bf_next;
            if (s < 7) bf_next = *(const short8*)(w1f + (((size_t)(s + 1) * 8 + wv) * 64 + l) * 8);
            short8 af0 = *(const short8*)&s_x[lr * 264 + s * 32 + ak];
            short8 af1 = *(const short8*)&s_x[(16 + lr) * 264 + s * 32 + ak];
            acc[0] = __builtin_amdgcn_mfma_f32_16x16x32_bf16(af0, bf_cur, acc[0], 0, 0, 0);
            acc[1] = __builtin_amdgcn_mfma_f32_16x16x32_bf16(af1, bf_cur, acc[1], 0, 0, 0);
            if (s < 7) bf_cur = bf_next;
        }
    }
    const int col = wv * 16 + lr;
    {
        float b1v = b1[col];
        #pragma unroll
        for (int mi = 0; mi < 2; ++mi)
            #pragma unroll
            for (int r = 0; r < 4; ++r) {
                float v = acc[mi][r] + b1v;
                s_y[(mi * 16 + (l >> 4) * 4 + r) * 136 + col] = f2b(v > 0.f ? v : 0.f);
            }
    }
    __syncthreads();
    f32x4 acc2[2] = {};
    #pragma unroll
    for (int s = 0; s < 4; ++s) {
        short8 af0 = *(const short8*)&s_y[lr * 136 + s * 32 + ak];
        short8 af1 = *(const short8*)&s_y[(16 + lr) * 136 + s * 32 + ak];
        short8 bf = *(const short8*)(w2f + (((size_t)s * 8 + wv) * 64 + l) * 8);
        acc2[0] = __builtin_amdgcn_mfma_f32_16x16x32_bf16(af0, bf, acc2[0], 0, 0, 0);
        acc2[1] = __builtin_amdgcn_mfma_f32_16x16x32_bf16(af1, bf, acc2[1], 0, 0, 0);
    }
    float b2v = b2[col];
    #pragma unroll
    for (int mi = 0; mi < 2; ++mi)
        #pragma unroll
        for (int r = 0; r < 4; ++r)
            out[(size_t)(bm + mi * 16 + (l >> 4) * 4 + r) * 128 + col] = acc2[mi][r] + b2v;
}

// ============ host launcher ============
extern "C" void kernel_launch(void* const* d_in, const int* in_sizes, int n_in,
                              void* d_out, int out_size, void* d_ws, size_t ws_size,
                              hipStream_t stream) {
    const float* nf  = (const float*)d_in[0];
    const float* adj = (const float*)d_in[1];
    const float* We  = (const float*)d_in[2];
    const float* Wih = (const float*)d_in[3];
    const float* Whh = (const float*)d_in[4];
    const float* bih = (const float*)d_in[5];
    const float* bhh = (const float*)d_in[6];
    const float* W1  = (const float*)d_in[7];
    const float* b1  = (const float*)d_in[8];
    const float* W2  = (const float*)d_in[9];
    const float* b2  = (const float*)d_in[10];
    float* out = (float*)d_out;

    char* p = (char*)d_ws;
    auto take = [&](size_t n) { char* r = p; p += (n + 255) & ~(size_t)255; return r; };
    int* cnt             = (int*)take(32768 * 4);
    unsigned short* cols = (unsigned short*)take((size_t)32768 * NBR_CAP * 2);
    float* h_g           = (float*)take((size_t)MROWS * 128 * 4);
    unsigned short* hb   = (unsigned short*)take((size_t)MROWS * 128 * 2);
    unsigned short* nfb  = (unsigned short*)take((size_t)MROWS * 128 * 2);
    unsigned short* ab   = (unsigned short*)take((size_t)MROWS * 512 * 2);
    unsigned short* wcf  = (unsigned short*)take(65536 * 2);
    unsigned short* wgf  = (unsigned short*)take(131072 * 2);
    unsigned short* w1f  = (unsigned short*)take(32768 * 2);
    unsigned short* w2f  = (unsigned short*)take(16384 * 2);
    float* bg            = (float*)take(512 * 4);

    combo<<<12288, 256, 0, stream>>>(adj, cols, cnt, nf, We, Wih, Whh, bih, bhh,
                                     W1, W2, h_g, hb, nfb, wcf, wgf, w1f, w2f, bg);

    for (int s = 0; s < 3; ++s) {
        aggregate<<<MROWS, 256, 0, stream>>>(hb, cols, cnt, ab);
        step2<<<256, 512, 0, stream>>>(ab, hb, h_g, wcf, wgf, bg);
    }

    mlp_k<<<256, 512, 0, stream>>>(nfb, hb, w1f, b1, w2f, b2, out);
}